// Round 12
// baseline (52.454 us; speedup 1.0000x reference)
//
#include <hip/hip_runtime.h>
#include <math.h>

#define BB 2
#define NN 512
#define NIN 64
#define NF 192
#define HH 128
#define NOUT 8
#define TP 136   // padded LDS row stride (ushorts) for hl_s / hr_s

typedef short short8 __attribute__((ext_vector_type(8)));
typedef float f32x4 __attribute__((ext_vector_type(4)));

__device__ __forceinline__ float celu1(float x) {
    return x > 0.0f ? x : expm1f(x);
}

__device__ __forceinline__ ushort f2b(float f) {
    union { float f; uint u; } v; v.f = f;
    uint r = v.u + 0x7fffu + ((v.u >> 16) & 1u);   // RNE
    return (ushort)(r >> 16);
}
__device__ __forceinline__ uint pack2(float a, float b) {
    return (uint)f2b(a) | ((uint)f2b(b) << 16);
}
__device__ __forceinline__ short8 pack8(float4 a, float4 b) {
    union { uint4 u; short8 s; } c;
    c.u.x = pack2(a.x, a.y); c.u.y = pack2(a.z, a.w);
    c.u.z = pack2(b.x, b.y); c.u.w = pack2(b.z, b.w);
    return c.s;
}

// t_s XOR swizzle (validated R6): byte = m*256 + (col*2 ^ (key(m)<<4)),
// key(m) = (m ^ (m>>3)) & 7.  ds_write_b64 (dm=8) and ds_read_b128 (dm=1)
// both land 2-way max (free).
__device__ __forceinline__ ushort* tsw(ushort* t_s, int m, int col) {
    int key = (m ^ (m >> 3)) & 7;
    int byte = m * 256 + ((col * 2) ^ (key << 4));
    return (ushort*)((char*)t_s + byte);
}

// ---------------------------------------------------------------------------
// Launch 1: Wb transpose only.  16 blocks x 512 (one dispatch round, no tail).
// o = bid>>1, h-half = bid&1.  (validated R11 else-branch)
// ---------------------------------------------------------------------------
__global__ __launch_bounds__(512) void wt_kernel(
    const float* __restrict__ Wb, ushort* __restrict__ Wt)
{
    __shared__ float lds_f[128 * 65];
    int bid = blockIdx.x;
    int tid = threadIdx.x;
    int o  = bid >> 1;
    int h0 = (bid & 1) * 64;
    for (int idx = tid; idx < 64 * 128; idx += 512) {
        int hh = idx >> 7;              // 0..63
        int g  = idx & 127;
        lds_f[g * 65 + hh] = Wb[(o * HH + h0 + hh) * HH + g];
    }
    __syncthreads();
    for (int idx = tid; idx < 128 * 64; idx += 512) {
        int g  = idx >> 6;              // 0..127
        int hh = idx & 63;
        Wt[(o * HH + g) * HH + h0 + hh] = f2b(lds_f[g * 65 + hh]);
    }
}

// ---------------------------------------------------------------------------
// fc accumulator for one 16x16 tile, K=192 (exact validated R4 body: loads
// batched first, then 6 MFMA).  gi = global row for this lane, af = weight
// fragments for this h-tile.
// ---------------------------------------------------------------------------
__device__ __forceinline__ f32x4 fc_acc(
    const float* __restrict__ x_l, const float* __restrict__ xa,
    const short8* af, int lr, int gi, int b, int lgrp)
{
    float4 braw[6][2];
    #pragma unroll
    for (int kk = 0; kk < 6; ++kk) {
        int part = kk >> 1;
        int c0 = (kk & 1) * 32 + lgrp * 8;
        int s; const float* src;
        if (part == 0)      { s = 0;            src = x_l; }  // faithful: zr part0 = x_l
        else if (part == 1) { s = lr ? +1 : -1; src = xa; }
        else                { s = lr ? -1 : +1; src = xa; }
        int row = gi + s;
        if ((unsigned)row < (unsigned)NN) {
            const float* pp = &src[(b * NN + row) * NIN + c0];
            braw[kk][0] = *(const float4*)pp;
            braw[kk][1] = *(const float4*)(pp + 4);
        } else {
            braw[kk][0] = float4{0.f, 0.f, 0.f, 0.f};
            braw[kk][1] = float4{0.f, 0.f, 0.f, 0.f};
        }
    }
    f32x4 acc = (f32x4)(0.0f);
    #pragma unroll
    for (int kk = 0; kk < 6; ++kk) {
        short8 bfrag = pack8(braw[kk][0], braw[kk][1]);
        acc = __builtin_amdgcn_mfma_f32_16x16x32_bf16(af[kk], bfrag, acc, 0, 0, 0);
    }
    return acc;
}

// ---------------------------------------------------------------------------
// Launch 2: mega-kernel.  Grid 256 x 512 (one dispatch round, 8 waves).
// bid -> j0 = (bid&3)*128, i0 = ((bid>>2)&31)*16, b = bid>>7.
//
// fc phase (per wave, h-tile h0 = wave*16):
//   - load+cvt Wl/Wr row-fragments once (reused across all 9 jobs)
//   - 1 hl job (rows i0..i0+16) -> hl_s;  8 hr jobs (rows j0+q*16) -> hr_s.
//   LDS rows padded to TP=136 ushorts: b128 reads land uniform
//   (lrow+lgrp) mod 8 bank slots = conflict-free.
// t phase (validated R6): o = wave, A = Wt global, B = hl_s; swizzled t_s.
// phase 2 (validated R6): bfr from hr_s; 32 MFMA; float4 epilogue.
// ---------------------------------------------------------------------------
__global__ __launch_bounds__(512) void mega_kernel(
    const float* __restrict__ x_l, const float* __restrict__ x_r,
    const float* __restrict__ Wl, const float* __restrict__ bl,
    const float* __restrict__ Wr, const float* __restrict__ br,
    const ushort* __restrict__ Wt, const float* __restrict__ bias_b,
    float* __restrict__ out)
{
    __shared__ ushort t_s[128 * 128];    // 32 KiB (swizzled)
    __shared__ ushort hr_s[128 * TP];    // 34 KiB
    __shared__ ushort hl_s[16 * TP];     // 4.25 KiB

    int bid = blockIdx.x;
    int j0 = (bid & 3) * 128;
    int i0 = ((bid >> 2) & 31) * 16;
    int b  = bid >> 7;
    int tid  = threadIdx.x;
    int wave = tid >> 6;        // 0..7
    int lane = tid & 63;
    int lrow = lane & 15;
    int lgrp = lane >> 4;

    // ---- fc phase ----
    int h0 = wave * 16;
    short8 afl[6], afr[6];
    #pragma unroll
    for (int kk = 0; kk < 6; ++kk) {
        const float* wp = &Wl[(h0 + lrow) * NF + kk * 32 + lgrp * 8];
        afl[kk] = pack8(*(const float4*)wp, *(const float4*)(wp + 4));
        const float* wq = &Wr[(h0 + lrow) * NF + kk * 32 + lgrp * 8];
        afr[kk] = pack8(*(const float4*)wq, *(const float4*)(wq + 4));
    }
    int h_base = h0 + lgrp * 4;
    float4 bvl = *(const float4*)&bl[h_base];
    float4 bvr = *(const float4*)&br[h_base];

    // hl job: rows i0..i0+16
    {
        f32x4 acc = fc_acc(x_l, x_l, afl, 0, i0 + lrow, b, lgrp);
        uint2 v;
        v.x = pack2(celu1(acc[0] + bvl.x), celu1(acc[1] + bvl.y));
        v.y = pack2(celu1(acc[2] + bvl.z), celu1(acc[3] + bvl.w));
        *(uint2*)&hl_s[lrow * TP + h_base] = v;
    }
    // hr jobs: rows j0+q*16
    #pragma unroll 2
    for (int q = 0; q < 8; ++q) {
        f32x4 acc = fc_acc(x_l, x_r, afr, 1, j0 + q * 16 + lrow, b, lgrp);
        uint2 v;
        v.x = pack2(celu1(acc[0] + bvr.x), celu1(acc[1] + bvr.y));
        v.y = pack2(celu1(acc[2] + bvr.z), celu1(acc[3] + bvr.w));
        *(uint2*)&hr_s[(q * 16 + lrow) * TP + h_base] = v;
    }
    __syncthreads();

    // ---- t phase: build t tile in swizzled LDS (wave w -> o = w) ----
    short8 hfrag[4];
    #pragma unroll
    for (int kk = 0; kk < 4; ++kk)
        hfrag[kk] = *(const short8*)&hl_s[lrow * TP + kk * 32 + lgrp * 8];

    int o_p1 = wave;
    #pragma unroll
    for (int gt = 0; gt < 8; ++gt) {
        int g_base = gt * 16;
        f32x4 acc = (f32x4)(0.0f);
        #pragma unroll
        for (int kk = 0; kk < 4; ++kk) {
            short8 afrag = *(const short8*)&Wt[(o_p1 * HH + g_base + lrow) * HH + kk * 32 + lgrp * 8];
            acc = __builtin_amdgcn_mfma_f32_16x16x32_bf16(afrag, hfrag[kk], acc, 0, 0, 0);
        }
        int m  = lrow * 8 + o_p1;        // lane: i = lrow (D col), g rows
        int gg = g_base + lgrp * 4;
        uint2 v;
        v.x = pack2(acc[0], acc[1]);
        v.y = pack2(acc[2], acc[3]);
        *(uint2*)tsw(t_s, m, gg) = v;
    }
    __syncthreads();

    // ---- phase 2: A from t_s (swizzled), B from hr_s ----
    short8 bfr[4];
    #pragma unroll
    for (int kk = 0; kk < 4; ++kk)
        bfr[kk] = *(const short8*)&hr_s[(wave * 16 + lrow) * TP + kk * 32 + lgrp * 8];

    f32x4 acc2[8];
    #pragma unroll
    for (int ms = 0; ms < 8; ++ms) acc2[ms] = (f32x4)(0.0f);

    #pragma unroll
    for (int kk = 0; kk < 4; ++kk) {
        int koff = kk * 32 + lgrp * 8;
        #pragma unroll
        for (int ms = 0; ms < 8; ++ms) {
            short8 afr2 = *(const short8*)tsw(t_s, ms * 16 + lrow, koff);
            acc2[ms] = __builtin_amdgcn_mfma_f32_16x16x32_bf16(afr2, bfr[kk], acc2[ms], 0, 0, 0);
        }
    }

    // ---- epilogue: 4 consecutive D rows -> same i, o0..o0+3; float4 store ----
    float4 b0 = *(const float4*)&bias_b[0];
    float4 b1 = *(const float4*)&bias_b[4];
    int j = j0 + wave * 16 + lrow;

    #pragma unroll
    for (int ms = 0; ms < 8; ++ms) {
        int m_base = ms * 16 + lgrp * 4;       // multiple of 4
        int i  = i0 + (m_base >> 3);
        int o0 = m_base & 7;                   // 0 or 4
        float4 bv = o0 ? b1 : b0;
        float4 v;
        v.x = acc2[ms][0] + bv.x;
        v.y = acc2[ms][1] + bv.y;
        v.z = acc2[ms][2] + bv.z;
        v.w = acc2[ms][3] + bv.w;
        float* dst = out + ((size_t)((b * NN + i) * NN + j)) * NOUT + o0;
        *(float4*)dst = v;
    }
}

// ---------------------------------------------------------------------------
extern "C" void kernel_launch(void* const* d_in, const int* in_sizes, int n_in,
                              void* d_out, int out_size, void* d_ws, size_t ws_size,
                              hipStream_t stream) {
    const float* x_l  = (const float*)d_in[0];
    const float* x_r  = (const float*)d_in[1];
    const float* Wl   = (const float*)d_in[2];
    const float* bl   = (const float*)d_in[3];
    const float* Wr   = (const float*)d_in[4];
    const float* br   = (const float*)d_in[5];
    const float* Wb   = (const float*)d_in[6];
    const float* bb   = (const float*)d_in[7];
    float* out = (float*)d_out;

    ushort* Wt = (ushort*)d_ws;                      // 8*128*128 = 131072 ushort

    wt_kernel<<<16, 512, 0, stream>>>(Wb, Wt);
    mega_kernel<<<256, 512, 0, stream>>>(x_l, x_r, Wl, bl, Wr, br, Wt, bb, out);
}